// Round 9
// baseline (389.506 us; speedup 1.0000x reference)
//
#include <hip/hip_runtime.h>
#include <math.h>

#define NN     50000
#define FF     256
#define HH     64
#define NHEADS 4
#define EE     800000
#define OUTD   16

typedef __attribute__((ext_vector_type(8))) short short8;
typedef __attribute__((ext_vector_type(4))) float f32x4;

__device__ inline unsigned short f2bf(float f) {
    unsigned u = __builtin_bit_cast(unsigned, f);
    unsigned r = (u + 0x7fff + ((u >> 16) & 1)) >> 16;
    return (unsigned short)r;
}
__device__ inline float bf2f(unsigned short s) {
    unsigned u = ((unsigned)s) << 16;
    return __builtin_bit_cast(float, u);
}

// ---------------------------------------------------------------------------
// CSR build (3-phase hierarchical scan — round-4 lesson).
// ---------------------------------------------------------------------------
__global__ void k_zero_int(int* __restrict__ p, int n) {
    int i = blockIdx.x * blockDim.x + threadIdx.x;
    if (i < n) p[i] = 0;
}

__global__ void k_count(const int* __restrict__ dst, int* __restrict__ cnt, int e) {
    int i = blockIdx.x * blockDim.x + threadIdx.x;
    if (i < e) atomicAdd(&cnt[dst[i]], 1);
}

__global__ __launch_bounds__(256) void k_scan_a(const int* __restrict__ cnt,
                                                int* __restrict__ partial, int n) {
    int i = blockIdx.x * 256 + threadIdx.x;
    int v = (i < n) ? cnt[i] : 0;
#pragma unroll
    for (int off = 32; off >= 1; off >>= 1) v += __shfl_xor(v, off, 64);
    __shared__ int ws[4];
    int wave = threadIdx.x >> 6;
    if ((threadIdx.x & 63) == 0) ws[wave] = v;
    __syncthreads();
    if (threadIdx.x == 0) partial[blockIdx.x] = ws[0] + ws[1] + ws[2] + ws[3];
}

__global__ __launch_bounds__(256) void k_scan_b(const int* __restrict__ partial,
                                                int* __restrict__ blockoff,
                                                int* __restrict__ total_out, int nb) {
    __shared__ int arr[256];
    int tid = threadIdx.x;
    arr[tid] = (tid < nb) ? partial[tid] : 0;
    __syncthreads();
#pragma unroll
    for (int off = 1; off < 256; off <<= 1) {
        int v = arr[tid];
        int add = (tid >= off) ? arr[tid - off] : 0;
        __syncthreads();
        arr[tid] = v + add;
        __syncthreads();
    }
    if (tid < nb) blockoff[tid] = arr[tid] - partial[tid];
    if (tid == 0) *total_out = arr[255];
}

__global__ __launch_bounds__(256) void k_scan_c(const int* __restrict__ cnt,
                                                const int* __restrict__ blockoff,
                                                int* __restrict__ row_start,
                                                int* __restrict__ cursor,
                                                float* __restrict__ dinv, int n) {
    __shared__ int arr[256];
    int tid = threadIdx.x;
    int i = blockIdx.x * 256 + tid;
    int c = (i < n) ? cnt[i] : 0;
    arr[tid] = c;
    __syncthreads();
#pragma unroll
    for (int off = 1; off < 256; off <<= 1) {
        int v = arr[tid];
        int add = (tid >= off) ? arr[tid - off] : 0;
        __syncthreads();
        arr[tid] = v + add;
        __syncthreads();
    }
    if (i < n) {
        int excl = arr[tid] - c + blockoff[blockIdx.x];
        row_start[i] = excl;
        cursor[i] = excl;
        dinv[i] = rsqrtf((float)(c + 1));
    }
}

__global__ void k_fill(const int* __restrict__ src, const int* __restrict__ dst,
                       int* __restrict__ cursor, int* __restrict__ col, int e) {
    int i = blockIdx.x * blockDim.x + threadIdx.x;
    if (i < e) {
        int d = dst[i];
        int pos = atomicAdd(&cursor[d], 1);
        col[pos] = src[i];
    }
}

// ---------------------------------------------------------------------------
// Pack W (K=KB*32 x NC=NT*16, row-major fp32) into MFMA B-fragment layout,
// split hi/lo bf16.
// ---------------------------------------------------------------------------
template <int KB, int NT>
__global__ void k_pack_w(const float* __restrict__ W,
                         unsigned short* __restrict__ bhi,
                         unsigned short* __restrict__ blo) {
    int t_ = blockIdx.x * blockDim.x + threadIdx.x;
    const int total = KB * NT * 64;
    if (t_ >= total) return;
    int lane = t_ & 63;
    int tile = (t_ >> 6) % NT;
    int kb = (t_ >> 6) / NT;
    int q = lane >> 4, c = lane & 15;
    const int NC = NT * 16;
    size_t off = ((size_t)(kb * NT + tile) * 64 + lane) * 8;
#pragma unroll
    for (int j = 0; j < 8; j++) {
        float w = W[(size_t)(kb * 32 + q * 8 + j) * NC + tile * 16 + c];
        unsigned short h = f2bf(w);
        bhi[off + j] = h;
        blo[off + j] = f2bf(w - bf2f(h));
    }
}

// ---------------------------------------------------------------------------
// MFMA GEMM (bf16x2), 128-row blocks: each wave computes 2 row-tiles so the
// per-wave LDS B-reads are amortized over 2x rows (round-8 analysis: DS pipe
// was the limiter — 4 waves re-reading 32 KB per kb). Fused s1 if SCORES.
// ---------------------------------------------------------------------------
template <int NT, bool SCALE, bool SCORES>
__global__ __launch_bounds__(256) void mfma_gemm(const float* __restrict__ A,
                                                 const unsigned short* __restrict__ Bhi,
                                                 const unsigned short* __restrict__ Blo,
                                                 unsigned short* __restrict__ Cbf,
                                                 const float* __restrict__ rowscale,
                                                 const float* __restrict__ a_s,
                                                 const float* __restrict__ a_d,
                                                 float* __restrict__ ssrc,
                                                 float* __restrict__ sdst,
                                                 int M) {
    const int K = 256, NC = NT * 16;
    __shared__ short8 bsh[NT * 64];
    __shared__ short8 bsl[NT * 64];
    int tid = threadIdx.x;
    int w = tid >> 6, lane = tid & 63, q = lane >> 4, c = lane & 15;
    int r0 = blockIdx.x * 128 + w * 16;
    int r1 = r0 + 64;
    int ar0 = min(r0 + c, M - 1);
    int ar1 = min(r1 + c, M - 1);
    const float* ap0 = A + (size_t)ar0 * K + q * 8;
    const float* ap1 = A + (size_t)ar1 * K + q * 8;

    f32x4 acc0[NT], acc1[NT];
#pragma unroll
    for (int t = 0; t < NT; t++) {
        acc0[t] = (f32x4){0.f, 0.f, 0.f, 0.f};
        acc1[t] = (f32x4){0.f, 0.f, 0.f, 0.f};
    }

    for (int kb = 0; kb < 8; kb++) {
        float av0[8], av1[8];
        *(float4*)(av0)     = *(const float4*)(ap0 + kb * 32);
        *(float4*)(av0 + 4) = *(const float4*)(ap0 + kb * 32 + 4);
        *(float4*)(av1)     = *(const float4*)(ap1 + kb * 32);
        *(float4*)(av1 + 4) = *(const float4*)(ap1 + kb * 32 + 4);
        short8 ahi0, alo0, ahi1, alo1;
#pragma unroll
        for (int j = 0; j < 8; j++) {
            unsigned short h0 = f2bf(av0[j]);
            ahi0[j] = (short)h0;
            alo0[j] = (short)f2bf(av0[j] - bf2f(h0));
            unsigned short h1 = f2bf(av1[j]);
            ahi1[j] = (short)h1;
            alo1[j] = (short)f2bf(av1[j] - bf2f(h1));
        }
        const short8* gh = (const short8*)(Bhi + (size_t)kb * NT * 512);
        const short8* gl = (const short8*)(Blo + (size_t)kb * NT * 512);
        __syncthreads();
        for (int i = tid; i < NT * 64; i += 256) {
            bsh[i] = gh[i];
            bsl[i] = gl[i];
        }
        __syncthreads();
#pragma unroll
        for (int t = 0; t < NT; t++) {
            short8 bhi = bsh[t * 64 + lane];
            short8 blo = bsl[t * 64 + lane];
            acc0[t] = __builtin_amdgcn_mfma_f32_16x16x32_bf16(ahi0, bhi, acc0[t], 0, 0, 0);
            acc0[t] = __builtin_amdgcn_mfma_f32_16x16x32_bf16(alo0, bhi, acc0[t], 0, 0, 0);
            acc0[t] = __builtin_amdgcn_mfma_f32_16x16x32_bf16(ahi0, blo, acc0[t], 0, 0, 0);
            acc1[t] = __builtin_amdgcn_mfma_f32_16x16x32_bf16(ahi1, bhi, acc1[t], 0, 0, 0);
            acc1[t] = __builtin_amdgcn_mfma_f32_16x16x32_bf16(alo1, bhi, acc1[t], 0, 0, 0);
            acc1[t] = __builtin_amdgcn_mfma_f32_16x16x32_bf16(ahi1, blo, acc1[t], 0, 0, 0);
        }
    }

    auto do_scores = [&](const f32x4 (&ac)[NT], int rbase) {
#pragma unroll
        for (int i = 0; i < 4; i++) {
            int r = rbase + q * 4 + i;
            float ss[4] = {0.f, 0.f, 0.f, 0.f};
            float sd[4] = {0.f, 0.f, 0.f, 0.f};
#pragma unroll
            for (int t = 0; t < NT; t++) {
                float v = ac[t][i];
                ss[t >> 2] += v * a_s[t * 16 + c];
                sd[t >> 2] += v * a_d[t * 16 + c];
            }
#pragma unroll
            for (int h = 0; h < 4; h++) {
#pragma unroll
                for (int off = 1; off <= 8; off <<= 1) {
                    ss[h] += __shfl_xor(ss[h], off, 16);
                    sd[h] += __shfl_xor(sd[h], off, 16);
                }
            }
            if (c == i && r < M) {
                *(float4*)(ssrc + (size_t)r * 4) = make_float4(ss[0], ss[1], ss[2], ss[3]);
                *(float4*)(sdst + (size_t)r * 4) = make_float4(sd[0], sd[1], sd[2], sd[3]);
            }
        }
    };
    if (SCORES) {
        do_scores(acc0, r0);
        do_scores(acc1, r1);
    }

    auto do_store = [&](const f32x4 (&ac)[NT], int rbase) {
#pragma unroll
        for (int i = 0; i < 4; i++) {
            int r = rbase + q * 4 + i;
            if (r < M) {
                float sc = SCALE ? rowscale[r] : 1.0f;
#pragma unroll
                for (int t = 0; t < NT; t++)
                    Cbf[(size_t)r * NC + t * 16 + c] = f2bf(ac[t][i] * sc);
            }
        }
    };
    do_store(acc0, r0);
    do_store(acc1, r1);
}

// ---------------------------------------------------------------------------
// MFMA GEMM with N=16, A exact bf16 (K=KB*32). W2 split hi/lo -> 2 MFMAs.
// Output is written as bf16 into an INTERLEAVED pair buffer at
// [(r*16+c)*2 + OFS] so final_agg gathers one dword per edge (round-8:
// two 2 B loads -> one 4 B load). Fused s2 if SC2.
// ---------------------------------------------------------------------------
template <int KB, bool SCALE, bool SC2, int OFS>
__global__ __launch_bounds__(256) void mfma_n16(const unsigned short* __restrict__ A,
                                                const unsigned short* __restrict__ Bhi,
                                                const unsigned short* __restrict__ Blo,
                                                unsigned short* __restrict__ Cbf,
                                                const float* __restrict__ rowscale,
                                                const float* __restrict__ a_s2,
                                                const float* __restrict__ a_d2,
                                                float* __restrict__ s2s,
                                                float* __restrict__ s2d, int M) {
    const int K = KB * 32;
    int tid = threadIdx.x;
    int w = tid >> 6, lane = tid & 63, q = lane >> 4, c = lane & 15;
    int row_base = blockIdx.x * 64 + w * 16;
    int ar = min(row_base + c, M - 1);
    const unsigned short* ap = A + (size_t)ar * K + q * 8;
    f32x4 acc = (f32x4){0.f, 0.f, 0.f, 0.f};
#pragma unroll
    for (int kb = 0; kb < KB; kb++) {
        short8 av = *(const short8*)(ap + kb * 32);
        size_t bo = ((size_t)kb * 64 + lane) * 8;
        short8 bh = *(const short8*)(Bhi + bo);
        short8 bl = *(const short8*)(Blo + bo);
        acc = __builtin_amdgcn_mfma_f32_16x16x32_bf16(av, bh, acc, 0, 0, 0);
        acc = __builtin_amdgcn_mfma_f32_16x16x32_bf16(av, bl, acc, 0, 0, 0);
    }
    if (SC2) {
#pragma unroll
        for (int i = 0; i < 4; i++) {
            float ps = acc[i] * a_s2[c];
            float pd = acc[i] * a_d2[c];
#pragma unroll
            for (int off = 1; off <= 8; off <<= 1) {
                ps += __shfl_xor(ps, off, 16);
                pd += __shfl_xor(pd, off, 16);
            }
            int r = row_base + q * 4 + i;
            if (c == i && r < M) {
                s2s[r] = ps;
                s2d[r] = pd;
            }
        }
    }
#pragma unroll
    for (int i = 0; i < 4; i++) {
        int r = row_base + q * 4 + i;
        if (r < M) {
            float sc = SCALE ? rowscale[r] : 1.0f;
            Cbf[((size_t)r * 16 + c) * 2 + OFS] = f2bf(acc[i] * sc);
        }
    }
}

// ---------------------------------------------------------------------------
// GCN1 aggregation, h1 bf16, pre-scaled by dinv; out bf16. 16 edges/iter
// (4 per lane-group) for MLP=4.
// ---------------------------------------------------------------------------
__global__ __launch_bounds__(256) void gcn1_agg(const unsigned short* __restrict__ h,
                                                const int* __restrict__ rs,
                                                const int* __restrict__ col,
                                                const float* __restrict__ dinv,
                                                const float* __restrict__ b,
                                                unsigned short* __restrict__ out) {
    int wid = (blockIdx.x * 256 + threadIdx.x) >> 6;
    int lane = threadIdx.x & 63;
    if (wid >= NN) return;
    int g = lane >> 4;
    int cidx = (lane & 15) * 4;
    float di = dinv[wid];
    int beg = rs[wid], end = rs[wid + 1];
    float4 acc = make_float4(0.f, 0.f, 0.f, 0.f);

    for (int j0 = beg; j0 < end; j0 += 64) {
        int cnt = min(64, end - j0);
        int sreg = 0;
        if (lane < cnt) sreg = col[j0 + lane];
        for (int e = 0; e < cnt; e += 16) {
            int m0 = e + g, m1 = e + g + 4, m2 = e + g + 8, m3 = e + g + 12;
            int s0 = __shfl(sreg, m0, 64);   // unconditional (round-2 lesson)
            int s1 = __shfl(sreg, m1, 64);
            int s2 = __shfl(sreg, m2, 64);
            int s3 = __shfl(sreg, m3, 64);
            ushort4 v0 = make_ushort4(0, 0, 0, 0), v1 = make_ushort4(0, 0, 0, 0);
            ushort4 v2 = make_ushort4(0, 0, 0, 0), v3 = make_ushort4(0, 0, 0, 0);
            if (m0 < cnt) v0 = *(const ushort4*)(h + (size_t)s0 * HH + cidx);
            if (m1 < cnt) v1 = *(const ushort4*)(h + (size_t)s1 * HH + cidx);
            if (m2 < cnt) v2 = *(const ushort4*)(h + (size_t)s2 * HH + cidx);
            if (m3 < cnt) v3 = *(const ushort4*)(h + (size_t)s3 * HH + cidx);
            acc.x += (bf2f(v0.x) + bf2f(v1.x)) + (bf2f(v2.x) + bf2f(v3.x));
            acc.y += (bf2f(v0.y) + bf2f(v1.y)) + (bf2f(v2.y) + bf2f(v3.y));
            acc.z += (bf2f(v0.z) + bf2f(v1.z)) + (bf2f(v2.z) + bf2f(v3.z));
            acc.w += (bf2f(v0.w) + bf2f(v1.w)) + (bf2f(v2.w) + bf2f(v3.w));
        }
    }
#pragma unroll
    for (int off = 16; off <= 32; off <<= 1) {
        acc.x += __shfl_xor(acc.x, off, 64);
        acc.y += __shfl_xor(acc.y, off, 64);
        acc.z += __shfl_xor(acc.z, off, 64);
        acc.w += __shfl_xor(acc.w, off, 64);
    }
    if (g == 0) {
        ushort4 sv = *(const ushort4*)(h + (size_t)wid * HH + cidx);
        float4 bv = *(const float4*)(b + cidx);
        ushort4 o;
        o.x = f2bf(fmaxf((acc.x + bf2f(sv.x)) * di + bv.x, 0.f));
        o.y = f2bf(fmaxf((acc.y + bf2f(sv.y)) * di + bv.y, 0.f));
        o.z = f2bf(fmaxf((acc.z + bf2f(sv.z)) * di + bv.z, 0.f));
        o.w = f2bf(fmaxf((acc.w + bf2f(sv.w)) * di + bv.w, 0.f));
        *(ushort4*)(out + (size_t)wid * HH + cidx) = o;
    }
}

// ---------------------------------------------------------------------------
// GAT1 aggregation: LDS-staged p/src; 4-edge unrolled gather. UNCHANGED from
// round 8 (control for the ~3.6 TB/s fabric-ceiling hypothesis).
// ---------------------------------------------------------------------------
__global__ __launch_bounds__(256) void gat1_agg(const unsigned short* __restrict__ hg,
                                                const int* __restrict__ rs,
                                                const int* __restrict__ col,
                                                const float* __restrict__ ssrc,
                                                const float* __restrict__ sdst,
                                                const float* __restrict__ b,
                                                unsigned short* __restrict__ out) {
    __shared__ int s_lds[4][64];
    __shared__ float p_lds[4][64 * 4];
    int tid = threadIdx.x;
    int w = tid >> 6, lane = tid & 63;
    int wid = blockIdx.x * 4 + w;       // grid exact: 12500*4 = NN
    int hh = lane >> 4;
    int* sl = s_lds[w];
    float* pl = p_lds[w];

    float4 sd4 = *(const float4*)(sdst + (size_t)wid * 4);
    float sdv[4] = {sd4.x, sd4.y, sd4.z, sd4.w};
    float4 sf4 = *(const float4*)(ssrc + (size_t)wid * 4);
    float sfv[4] = {sf4.x, sf4.y, sf4.z, sf4.w};
    float psf[4];
#pragma unroll
    for (int h = 0; h < 4; h++) {
        float e = sfv[h] + sdv[h];
        e = (e >= 0.f) ? e : 0.2f * e;
        psf[h] = __expf(e);
    }
    float pse = (hh & 2) ? ((hh & 1) ? psf[3] : psf[2]) : ((hh & 1) ? psf[1] : psf[0]);
    const unsigned short* hbase = hg + lane * 4;
    ushort4 hvs = *(const ushort4*)(hbase + (size_t)wid * 256);
    float4 acc;
    acc.x = bf2f(hvs.x) * pse; acc.y = bf2f(hvs.y) * pse;
    acc.z = bf2f(hvs.z) * pse; acc.w = bf2f(hvs.w) * pse;

    float lsum[4] = {0.f, 0.f, 0.f, 0.f};
    int beg = rs[wid], end = rs[wid + 1];
    for (int j0 = beg; j0 < end; j0 += 64) {
        int cnt = min(64, end - j0);
        if (lane < cnt) {
            int sreg = col[j0 + lane];
            float4 sv = *(const float4*)(ssrc + (size_t)sreg * 4);
            float svv[4] = {sv.x, sv.y, sv.z, sv.w};
            float pv[4];
#pragma unroll
            for (int h = 0; h < 4; h++) {
                float e = svv[h] + sdv[h];
                e = (e >= 0.f) ? e : 0.2f * e;
                pv[h] = __expf(e);
                lsum[h] += pv[h];
            }
            sl[lane] = sreg;
            *(float4*)&pl[lane * 4] = make_float4(pv[0], pv[1], pv[2], pv[3]);
        }
        int e = 0;
        for (; e + 4 <= cnt; e += 4) {
            int s0 = sl[e], s1 = sl[e + 1], s2 = sl[e + 2], s3 = sl[e + 3];
            float p0 = pl[e * 4 + hh], p1 = pl[(e + 1) * 4 + hh];
            float p2 = pl[(e + 2) * 4 + hh], p3 = pl[(e + 3) * 4 + hh];
            ushort4 h0 = *(const ushort4*)(hbase + (size_t)s0 * 256);
            ushort4 h1 = *(const ushort4*)(hbase + (size_t)s1 * 256);
            ushort4 h2 = *(const ushort4*)(hbase + (size_t)s2 * 256);
            ushort4 h3 = *(const ushort4*)(hbase + (size_t)s3 * 256);
            acc.x += bf2f(h0.x) * p0; acc.y += bf2f(h0.y) * p0;
            acc.z += bf2f(h0.z) * p0; acc.w += bf2f(h0.w) * p0;
            acc.x += bf2f(h1.x) * p1; acc.y += bf2f(h1.y) * p1;
            acc.z += bf2f(h1.z) * p1; acc.w += bf2f(h1.w) * p1;
            acc.x += bf2f(h2.x) * p2; acc.y += bf2f(h2.y) * p2;
            acc.z += bf2f(h2.z) * p2; acc.w += bf2f(h2.w) * p2;
            acc.x += bf2f(h3.x) * p3; acc.y += bf2f(h3.y) * p3;
            acc.z += bf2f(h3.z) * p3; acc.w += bf2f(h3.w) * p3;
        }
        for (; e < cnt; e++) {
            int s = sl[e];
            float p = pl[e * 4 + hh];
            ushort4 hv = *(const ushort4*)(hbase + (size_t)s * 256);
            acc.x += bf2f(hv.x) * p; acc.y += bf2f(hv.y) * p;
            acc.z += bf2f(hv.z) * p; acc.w += bf2f(hv.w) * p;
        }
    }
#pragma unroll
    for (int h = 0; h < 4; h++) {
        float v = lsum[h];
        for (int off = 32; off >= 1; off >>= 1) v += __shfl_xor(v, off, 64);
        lsum[h] = v + psf[h];
    }
    float lt = (hh & 2) ? ((hh & 1) ? lsum[3] : lsum[2]) : ((hh & 1) ? lsum[1] : lsum[0]);
    float li = 1.0f / lt;
    float4 bv = *(const float4*)(b + lane * 4);
    ushort4 o;
    o.x = f2bf(fmaxf(acc.x * li + bv.x, 0.f));
    o.y = f2bf(fmaxf(acc.y * li + bv.y, 0.f));
    o.z = f2bf(fmaxf(acc.z * li + bv.z, 0.f));
    o.w = f2bf(fmaxf(acc.w * li + bv.w, 0.f));
    *(ushort4*)(out + (size_t)wid * 256 + lane * 4) = o;
}

// ---------------------------------------------------------------------------
// Final aggregation: fused GCN2 + GAT2 over the interleaved pair buffer
// (one dword per edge per lane: lo=h2, hi=h2g). 16 lanes per node.
// ---------------------------------------------------------------------------
__global__ __launch_bounds__(256) void final_agg(const unsigned* __restrict__ hp,
                                                 const int* __restrict__ rs,
                                                 const int* __restrict__ col,
                                                 const float* __restrict__ dinv,
                                                 const float* __restrict__ s2s,
                                                 const float* __restrict__ s2d,
                                                 const float* __restrict__ bg2,
                                                 const float* __restrict__ bga2,
                                                 float* __restrict__ out) {
    int t = blockIdx.x * 256 + threadIdx.x;
    int node = t >> 4;
    int c = t & 15;
    float di = dinv[node];
    float sd = s2d[node];
    float es = s2s[node] + sd;
    es = (es >= 0.f) ? es : 0.2f * es;
    float psf = __expf(es);
    unsigned pvs = hp[(size_t)node * 16 + c];
    float accg = bf2f((unsigned short)pvs);
    float acca = bf2f((unsigned short)(pvs >> 16)) * psf;
    float lp = 0.f;
    int beg = rs[node], end = rs[node + 1];
    for (int j0 = beg; j0 < end; j0 += 16) {
        int cnt = min(16, end - j0);
        int sreg = 0;
        float pr = 0.f;
        if (c < cnt) {
            sreg = col[j0 + c];
            float e = s2s[sreg] + sd;
            e = (e >= 0.f) ? e : 0.2f * e;
            pr = __expf(e);
            lp += pr;
        }
        for (int e = 0; e < cnt; e += 4) {
            int si[4];
            float pi[4];
#pragma unroll
            for (int u = 0; u < 4; u++) {
                si[u] = __shfl(sreg, (e + u) & 15, 16);  // sources active in-group
                pi[u] = __shfl(pr, (e + u) & 15, 16);
            }
            unsigned hv[4];
#pragma unroll
            for (int u = 0; u < 4; u++) hv[u] = hp[(size_t)si[u] * 16 + c];
#pragma unroll
            for (int u = 0; u < 4; u++) {
                if (e + u < cnt) {
                    accg += bf2f((unsigned short)hv[u]);
                    acca += bf2f((unsigned short)(hv[u] >> 16)) * pi[u];
                }
            }
        }
    }
    for (int off = 8; off >= 1; off >>= 1) lp += __shfl_xor(lp, off, 16);
    float l = lp + psf;
    out[(size_t)node * 32 + c] = accg * di + bg2[c];
    out[(size_t)node * 32 + 16 + c] = acca / l + bga2[c];
}

// ---------------------------------------------------------------------------
// Launch
// ---------------------------------------------------------------------------
extern "C" void kernel_launch(void* const* d_in, const int* in_sizes, int n_in,
                              void* d_out, int out_size, void* d_ws, size_t ws_size,
                              hipStream_t stream) {
    const float* x      = (const float*)d_in[0];
    const int*   ei     = (const int*)d_in[1];
    const float* Wg1    = (const float*)d_in[2];
    const float* bg1    = (const float*)d_in[3];
    const float* Wg2    = (const float*)d_in[4];
    const float* bg2    = (const float*)d_in[5];
    const float* Wgat1  = (const float*)d_in[6];
    const float* a_src1 = (const float*)d_in[7];
    const float* a_dst1 = (const float*)d_in[8];
    const float* bgat1  = (const float*)d_in[9];
    const float* Wgat2  = (const float*)d_in[10];
    const float* a_src2 = (const float*)d_in[11];
    const float* a_dst2 = (const float*)d_in[12];
    const float* bgat2  = (const float*)d_in[13];
    float* out = (float*)d_out;

    const int* e_src = ei;
    const int* e_dst = ei + EE;

    char* wsb = (char*)d_ws;
    size_t o = 0;
    auto alloc = [&](size_t bytes) -> void* {
        void* p = wsb + o;
        o += (bytes + 255) & ~(size_t)255;
        return p;
    };
    float* dinv            = (float*)alloc(NN * 4);
    float* ssrc1           = (float*)alloc((size_t)NN * 16);
    float* sdst1           = (float*)alloc((size_t)NN * 16);
    unsigned short* h1b    = (unsigned short*)alloc((size_t)NN * HH * 2);
    unsigned short* xg1    = (unsigned short*)alloc((size_t)NN * HH * 2);
    unsigned short* hgb    = (unsigned short*)alloc((size_t)NN * 256 * 2);
    unsigned short* xgat1  = (unsigned short*)alloc((size_t)NN * 256 * 2);
    unsigned short* pairb  = (unsigned short*)alloc((size_t)NN * 16 * 4);  // interleaved h2|h2g
    float* s2src           = (float*)alloc(NN * 4);
    float* s2dst           = (float*)alloc(NN * 4);
    unsigned short* bhi1   = (unsigned short*)alloc(256 * 64 * 2);
    unsigned short* blo1   = (unsigned short*)alloc(256 * 64 * 2);
    unsigned short* bhi2   = (unsigned short*)alloc(256 * 256 * 2);
    unsigned short* blo2   = (unsigned short*)alloc(256 * 256 * 2);
    unsigned short* bhiG2  = (unsigned short*)alloc(64 * 16 * 2);
    unsigned short* bloG2  = (unsigned short*)alloc(64 * 16 * 2);
    unsigned short* bhiA2  = (unsigned short*)alloc(256 * 16 * 2);
    unsigned short* bloA2  = (unsigned short*)alloc(256 * 16 * 2);
    int* cnt               = (int*)alloc(NN * 4);
    int* rowstart          = (int*)alloc((NN + 1) * 4);
    int* cursor            = (int*)alloc(NN * 4);
    int* colarr            = (int*)alloc((size_t)EE * 4);
    int* partial           = (int*)alloc(256 * 4);
    int* blockoff          = (int*)alloc(256 * 4);

    const int TB = 256;
    const int NB = (NN + 255) / 256;
    // CSR build + weight packing
    k_zero_int<<<(NN + TB - 1) / TB, TB, 0, stream>>>(cnt, NN);
    k_count<<<(EE + TB - 1) / TB, TB, 0, stream>>>(e_dst, cnt, EE);
    k_scan_a<<<NB, TB, 0, stream>>>(cnt, partial, NN);
    k_scan_b<<<1, TB, 0, stream>>>(partial, blockoff, rowstart + NN, NB);
    k_scan_c<<<NB, TB, 0, stream>>>(cnt, blockoff, rowstart, cursor, dinv, NN);
    k_fill<<<(EE + TB - 1) / TB, TB, 0, stream>>>(e_src, e_dst, cursor, colarr, EE);
    k_pack_w<8, 4><<<(8 * 4 * 64 + TB - 1) / TB, TB, 0, stream>>>(Wg1, bhi1, blo1);
    k_pack_w<8, 16><<<(8 * 16 * 64 + TB - 1) / TB, TB, 0, stream>>>(Wgat1, bhi2, blo2);
    k_pack_w<2, 1><<<1, TB, 0, stream>>>(Wg2, bhiG2, bloG2);
    k_pack_w<8, 1><<<2, TB, 0, stream>>>(Wgat2, bhiA2, bloA2);

    const int GB128 = (NN + 127) / 128;  // 391 blocks for the big GEMMs
    const int GB = (NN + 63) / 64;
    const int G16 = (NN * 16) / 256;     // exact: 3125

    // GCN path
    mfma_gemm<4, true, false><<<GB128, TB, 0, stream>>>(x, bhi1, blo1, h1b, dinv,
                                                        nullptr, nullptr, nullptr, nullptr, NN);
    gcn1_agg<<<(NN * 64) / TB, TB, 0, stream>>>(h1b, rowstart, colarr, dinv, bg1, xg1);
    mfma_n16<2, true, false, 0><<<GB, TB, 0, stream>>>(xg1, bhiG2, bloG2, pairb, dinv,
                                                       nullptr, nullptr, nullptr, nullptr, NN);

    // GAT path
    mfma_gemm<16, false, true><<<GB128, TB, 0, stream>>>(x, bhi2, blo2, hgb, nullptr,
                                                         a_src1, a_dst1, ssrc1, sdst1, NN);
    gat1_agg<<<NN / 4, TB, 0, stream>>>(hgb, rowstart, colarr, ssrc1, sdst1, bgat1, xgat1);
    mfma_n16<8, false, true, 1><<<GB, TB, 0, stream>>>(xgat1, bhiA2, bloA2, pairb, nullptr,
                                                       a_src2, a_dst2, s2src, s2dst, NN);

    // Fused GCN2+GAT2 aggregation -> d_out
    final_agg<<<G16, TB, 0, stream>>>((const unsigned*)pairb, rowstart, colarr, dinv,
                                      s2src, s2dst, bg2, bgat2, out);
}

// Round 10
// 370.639 us; speedup vs baseline: 1.0509x; 1.0509x over previous
//
#include <hip/hip_runtime.h>
#include <math.h>

#define NN     50000
#define FF     256
#define HH     64
#define NHEADS 4
#define EE     800000
#define OUTD   16

typedef __attribute__((ext_vector_type(8))) short short8;
typedef __attribute__((ext_vector_type(4))) float f32x4;

__device__ inline unsigned short f2bf(float f) {
    unsigned u = __builtin_bit_cast(unsigned, f);
    unsigned r = (u + 0x7fff + ((u >> 16) & 1)) >> 16;
    return (unsigned short)r;
}
__device__ inline float bf2f(unsigned short s) {
    unsigned u = ((unsigned)s) << 16;
    return __builtin_bit_cast(float, u);
}

// ---------------------------------------------------------------------------
// CSR build (3-phase hierarchical scan — round-4 lesson).
// ---------------------------------------------------------------------------
__global__ void k_zero_int(int* __restrict__ p, int n) {
    int i = blockIdx.x * blockDim.x + threadIdx.x;
    if (i < n) p[i] = 0;
}

__global__ void k_count(const int* __restrict__ dst, int* __restrict__ cnt, int e) {
    int i = blockIdx.x * blockDim.x + threadIdx.x;
    if (i < e) atomicAdd(&cnt[dst[i]], 1);
}

__global__ __launch_bounds__(256) void k_scan_a(const int* __restrict__ cnt,
                                                int* __restrict__ partial, int n) {
    int i = blockIdx.x * 256 + threadIdx.x;
    int v = (i < n) ? cnt[i] : 0;
#pragma unroll
    for (int off = 32; off >= 1; off >>= 1) v += __shfl_xor(v, off, 64);
    __shared__ int ws[4];
    int wave = threadIdx.x >> 6;
    if ((threadIdx.x & 63) == 0) ws[wave] = v;
    __syncthreads();
    if (threadIdx.x == 0) partial[blockIdx.x] = ws[0] + ws[1] + ws[2] + ws[3];
}

__global__ __launch_bounds__(256) void k_scan_b(const int* __restrict__ partial,
                                                int* __restrict__ blockoff,
                                                int* __restrict__ total_out, int nb) {
    __shared__ int arr[256];
    int tid = threadIdx.x;
    arr[tid] = (tid < nb) ? partial[tid] : 0;
    __syncthreads();
#pragma unroll
    for (int off = 1; off < 256; off <<= 1) {
        int v = arr[tid];
        int add = (tid >= off) ? arr[tid - off] : 0;
        __syncthreads();
        arr[tid] = v + add;
        __syncthreads();
    }
    if (tid < nb) blockoff[tid] = arr[tid] - partial[tid];
    if (tid == 0) *total_out = arr[255];
}

__global__ __launch_bounds__(256) void k_scan_c(const int* __restrict__ cnt,
                                                const int* __restrict__ blockoff,
                                                int* __restrict__ row_start,
                                                int* __restrict__ cursor,
                                                float* __restrict__ dinv, int n) {
    __shared__ int arr[256];
    int tid = threadIdx.x;
    int i = blockIdx.x * 256 + tid;
    int c = (i < n) ? cnt[i] : 0;
    arr[tid] = c;
    __syncthreads();
#pragma unroll
    for (int off = 1; off < 256; off <<= 1) {
        int v = arr[tid];
        int add = (tid >= off) ? arr[tid - off] : 0;
        __syncthreads();
        arr[tid] = v + add;
        __syncthreads();
    }
    if (i < n) {
        int excl = arr[tid] - c + blockoff[blockIdx.x];
        row_start[i] = excl;
        cursor[i] = excl;
        dinv[i] = rsqrtf((float)(c + 1));
    }
}

__global__ void k_fill(const int* __restrict__ src, const int* __restrict__ dst,
                       int* __restrict__ cursor, int* __restrict__ col, int e) {
    int i = blockIdx.x * blockDim.x + threadIdx.x;
    if (i < e) {
        int d = dst[i];
        int pos = atomicAdd(&cursor[d], 1);
        col[pos] = src[i];
    }
}

// ---------------------------------------------------------------------------
// Pack W (K=KB*32 x NC=NT*16, row-major fp32) into MFMA B-fragment layout,
// split hi/lo bf16. NTOT/TOFF place the NT tiles inside a combined buffer
// with NTOT tiles per k-block at tile offset TOFF (for the fused GEMM).
// ---------------------------------------------------------------------------
template <int KB, int NT, int NTOT, int TOFF>
__global__ void k_pack_w(const float* __restrict__ W,
                         unsigned short* __restrict__ bhi,
                         unsigned short* __restrict__ blo) {
    int t_ = blockIdx.x * blockDim.x + threadIdx.x;
    const int total = KB * NT * 64;
    if (t_ >= total) return;
    int lane = t_ & 63;
    int tile = (t_ >> 6) % NT;
    int kb = (t_ >> 6) / NT;
    int q = lane >> 4, c = lane & 15;
    const int NC = NT * 16;
    size_t off = ((size_t)(kb * NTOT + TOFF + tile) * 64 + lane) * 8;
#pragma unroll
    for (int j = 0; j < 8; j++) {
        float w = W[(size_t)(kb * 32 + q * 8 + j) * NC + tile * 16 + c];
        unsigned short h = f2bf(w);
        bhi[off + j] = h;
        blo[off + j] = f2bf(w - bf2f(h));
    }
}

// ---------------------------------------------------------------------------
// FUSED big GEMM (bf16x2): one pass over x computes BOTH h1 (4 tiles, Wg1,
// scaled by dinv) and hgat (16 tiles, Wgat1) + fused s1 scores.
// Round-9 lesson: keep ONE accumulator set per wave (64-row blocks) — the
// 2-tile variant doubled acc VGPRs and regressed. Fusion amortizes instead:
// A is read/split once for 20 output tiles, B staged in LDS once per block.
// ---------------------------------------------------------------------------
#define NTT 20
__global__ __launch_bounds__(256) void mfma_gemm_fused(const float* __restrict__ A,
                                                       const unsigned short* __restrict__ Bhi,
                                                       const unsigned short* __restrict__ Blo,
                                                       unsigned short* __restrict__ Ch1,
                                                       unsigned short* __restrict__ Chg,
                                                       const float* __restrict__ dinv,
                                                       const float* __restrict__ a_s,
                                                       const float* __restrict__ a_d,
                                                       float* __restrict__ ssrc,
                                                       float* __restrict__ sdst,
                                                       int M) {
    const int K = 256;
    __shared__ short8 bsh[NTT * 64];
    __shared__ short8 bsl[NTT * 64];
    int tid = threadIdx.x;
    int w = tid >> 6, lane = tid & 63, q = lane >> 4, c = lane & 15;
    int row_base = blockIdx.x * 64 + w * 16;
    int ar = min(row_base + c, M - 1);
    const float* ap = A + (size_t)ar * K + q * 8;

    f32x4 acc[NTT];
#pragma unroll
    for (int t = 0; t < NTT; t++) acc[t] = (f32x4){0.f, 0.f, 0.f, 0.f};

    for (int kb = 0; kb < 8; kb++) {
        float av[8];
        *(float4*)(av)     = *(const float4*)(ap + kb * 32);
        *(float4*)(av + 4) = *(const float4*)(ap + kb * 32 + 4);
        short8 ahi, alo;
#pragma unroll
        for (int j = 0; j < 8; j++) {
            unsigned short h = f2bf(av[j]);
            ahi[j] = (short)h;
            alo[j] = (short)f2bf(av[j] - bf2f(h));
        }
        const short8* gh = (const short8*)(Bhi + (size_t)kb * NTT * 512);
        const short8* gl = (const short8*)(Blo + (size_t)kb * NTT * 512);
        __syncthreads();
        for (int i = tid; i < NTT * 64; i += 256) {
            bsh[i] = gh[i];
            bsl[i] = gl[i];
        }
        __syncthreads();
#pragma unroll
        for (int t = 0; t < NTT; t++) {
            short8 bhi = bsh[t * 64 + lane];
            short8 blo = bsl[t * 64 + lane];
            acc[t] = __builtin_amdgcn_mfma_f32_16x16x32_bf16(ahi, bhi, acc[t], 0, 0, 0);
            acc[t] = __builtin_amdgcn_mfma_f32_16x16x32_bf16(alo, bhi, acc[t], 0, 0, 0);
            acc[t] = __builtin_amdgcn_mfma_f32_16x16x32_bf16(ahi, blo, acc[t], 0, 0, 0);
        }
    }

    // s1 scores over the 16 GAT tiles (tiles 4..19; head = (t-4)>>2)
#pragma unroll
    for (int i = 0; i < 4; i++) {
        int r = row_base + q * 4 + i;
        float ss[4] = {0.f, 0.f, 0.f, 0.f};
        float sd[4] = {0.f, 0.f, 0.f, 0.f};
#pragma unroll
        for (int t = 0; t < 16; t++) {
            float v = acc[t + 4][i];
            ss[t >> 2] += v * a_s[t * 16 + c];
            sd[t >> 2] += v * a_d[t * 16 + c];
        }
#pragma unroll
        for (int h = 0; h < 4; h++) {
#pragma unroll
            for (int off = 1; off <= 8; off <<= 1) {
                ss[h] += __shfl_xor(ss[h], off, 16);
                sd[h] += __shfl_xor(sd[h], off, 16);
            }
        }
        if (c == i && r < M) {
            *(float4*)(ssrc + (size_t)r * 4) = make_float4(ss[0], ss[1], ss[2], ss[3]);
            *(float4*)(sdst + (size_t)r * 4) = make_float4(sd[0], sd[1], sd[2], sd[3]);
        }
    }

#pragma unroll
    for (int i = 0; i < 4; i++) {
        int r = row_base + q * 4 + i;
        if (r < M) {
            float sc = dinv[r];
#pragma unroll
            for (int t = 0; t < 4; t++)
                Ch1[(size_t)r * 64 + t * 16 + c] = f2bf(acc[t][i] * sc);
#pragma unroll
            for (int t = 0; t < 16; t++)
                Chg[(size_t)r * 256 + t * 16 + c] = f2bf(acc[t + 4][i]);
        }
    }
}

// ---------------------------------------------------------------------------
// MFMA GEMM with N=16, A exact bf16 (K=KB*32). W2 split hi/lo -> 2 MFMAs.
// Output bf16 into the INTERLEAVED pair buffer at [(r*16+c)*2 + OFS]
// (round-8: one dword gather in final_agg instead of two 2 B loads).
// ---------------------------------------------------------------------------
template <int KB, bool SCALE, bool SC2, int OFS>
__global__ __launch_bounds__(256) void mfma_n16(const unsigned short* __restrict__ A,
                                                const unsigned short* __restrict__ Bhi,
                                                const unsigned short* __restrict__ Blo,
                                                unsigned short* __restrict__ Cbf,
                                                const float* __restrict__ rowscale,
                                                const float* __restrict__ a_s2,
                                                const float* __restrict__ a_d2,
                                                float* __restrict__ s2s,
                                                float* __restrict__ s2d, int M) {
    const int K = KB * 32;
    int tid = threadIdx.x;
    int w = tid >> 6, lane = tid & 63, q = lane >> 4, c = lane & 15;
    int row_base = blockIdx.x * 64 + w * 16;
    int ar = min(row_base + c, M - 1);
    const unsigned short* ap = A + (size_t)ar * K + q * 8;
    f32x4 acc = (f32x4){0.f, 0.f, 0.f, 0.f};
#pragma unroll
    for (int kb = 0; kb < KB; kb++) {
        short8 av = *(const short8*)(ap + kb * 32);
        size_t bo = ((size_t)kb * 64 + lane) * 8;
        short8 bh = *(const short8*)(Bhi + bo);
        short8 bl = *(const short8*)(Blo + bo);
        acc = __builtin_amdgcn_mfma_f32_16x16x32_bf16(av, bh, acc, 0, 0, 0);
        acc = __builtin_amdgcn_mfma_f32_16x16x32_bf16(av, bl, acc, 0, 0, 0);
    }
    if (SC2) {
#pragma unroll
        for (int i = 0; i < 4; i++) {
            float ps = acc[i] * a_s2[c];
            float pd = acc[i] * a_d2[c];
#pragma unroll
            for (int off = 1; off <= 8; off <<= 1) {
                ps += __shfl_xor(ps, off, 16);
                pd += __shfl_xor(pd, off, 16);
            }
            int r = row_base + q * 4 + i;
            if (c == i && r < M) {
                s2s[r] = ps;
                s2d[r] = pd;
            }
        }
    }
#pragma unroll
    for (int i = 0; i < 4; i++) {
        int r = row_base + q * 4 + i;
        if (r < M) {
            float sc = SCALE ? rowscale[r] : 1.0f;
            Cbf[((size_t)r * 16 + c) * 2 + OFS] = f2bf(acc[i] * sc);
        }
    }
}

// ---------------------------------------------------------------------------
// GCN1 aggregation, h1 bf16, pre-scaled by dinv; out bf16. 16 edges/iter
// (4 per lane-group) for MLP=4.
// ---------------------------------------------------------------------------
__global__ __launch_bounds__(256) void gcn1_agg(const unsigned short* __restrict__ h,
                                                const int* __restrict__ rs,
                                                const int* __restrict__ col,
                                                const float* __restrict__ dinv,
                                                const float* __restrict__ b,
                                                unsigned short* __restrict__ out) {
    int wid = (blockIdx.x * 256 + threadIdx.x) >> 6;
    int lane = threadIdx.x & 63;
    if (wid >= NN) return;
    int g = lane >> 4;
    int cidx = (lane & 15) * 4;
    float di = dinv[wid];
    int beg = rs[wid], end = rs[wid + 1];
    float4 acc = make_float4(0.f, 0.f, 0.f, 0.f);

    for (int j0 = beg; j0 < end; j0 += 64) {
        int cnt = min(64, end - j0);
        int sreg = 0;
        if (lane < cnt) sreg = col[j0 + lane];
        for (int e = 0; e < cnt; e += 16) {
            int m0 = e + g, m1 = e + g + 4, m2 = e + g + 8, m3 = e + g + 12;
            int s0 = __shfl(sreg, m0, 64);   // unconditional (round-2 lesson)
            int s1 = __shfl(sreg, m1, 64);
            int s2 = __shfl(sreg, m2, 64);
            int s3 = __shfl(sreg, m3, 64);
            ushort4 v0 = make_ushort4(0, 0, 0, 0), v1 = make_ushort4(0, 0, 0, 0);
            ushort4 v2 = make_ushort4(0, 0, 0, 0), v3 = make_ushort4(0, 0, 0, 0);
            if (m0 < cnt) v0 = *(const ushort4*)(h + (size_t)s0 * HH + cidx);
            if (m1 < cnt) v1 = *(const ushort4*)(h + (size_t)s1 * HH + cidx);
            if (m2 < cnt) v2 = *(const ushort4*)(h + (size_t)s2 * HH + cidx);
            if (m3 < cnt) v3 = *(const ushort4*)(h + (size_t)s3 * HH + cidx);
            acc.x += (bf2f(v0.x) + bf2f(v1.x)) + (bf2f(v2.x) + bf2f(v3.x));
            acc.y += (bf2f(v0.y) + bf2f(v1.y)) + (bf2f(v2.y) + bf2f(v3.y));
            acc.z += (bf2f(v0.z) + bf2f(v1.z)) + (bf2f(v2.z) + bf2f(v3.z));
            acc.w += (bf2f(v0.w) + bf2f(v1.w)) + (bf2f(v2.w) + bf2f(v3.w));
        }
    }
#pragma unroll
    for (int off = 16; off <= 32; off <<= 1) {
        acc.x += __shfl_xor(acc.x, off, 64);
        acc.y += __shfl_xor(acc.y, off, 64);
        acc.z += __shfl_xor(acc.z, off, 64);
        acc.w += __shfl_xor(acc.w, off, 64);
    }
    if (g == 0) {
        ushort4 sv = *(const ushort4*)(h + (size_t)wid * HH + cidx);
        float4 bv = *(const float4*)(b + cidx);
        ushort4 o;
        o.x = f2bf(fmaxf((acc.x + bf2f(sv.x)) * di + bv.x, 0.f));
        o.y = f2bf(fmaxf((acc.y + bf2f(sv.y)) * di + bv.y, 0.f));
        o.z = f2bf(fmaxf((acc.z + bf2f(sv.z)) * di + bv.z, 0.f));
        o.w = f2bf(fmaxf((acc.w + bf2f(sv.w)) * di + bv.w, 0.f));
        *(ushort4*)(out + (size_t)wid * HH + cidx) = o;
    }
}

// ---------------------------------------------------------------------------
// GAT1 aggregation: LDS-staged p/src; 4-edge unrolled gather. At its
// fabric-ceiling floor (~3.6 TB/s FETCH-side) — kept unchanged.
// ---------------------------------------------------------------------------
__global__ __launch_bounds__(256) void gat1_agg(const unsigned short* __restrict__ hg,
                                                const int* __restrict__ rs,
                                                const int* __restrict__ col,
                                                const float* __restrict__ ssrc,
                                                const float* __restrict__ sdst,
                                                const float* __restrict__ b,
                                                unsigned short* __restrict__ out) {
    __shared__ int s_lds[4][64];
    __shared__ float p_lds[4][64 * 4];
    int tid = threadIdx.x;
    int w = tid >> 6, lane = tid & 63;
    int wid = blockIdx.x * 4 + w;       // grid exact: 12500*4 = NN
    int hh = lane >> 4;
    int* sl = s_lds[w];
    float* pl = p_lds[w];

    float4 sd4 = *(const float4*)(sdst + (size_t)wid * 4);
    float sdv[4] = {sd4.x, sd4.y, sd4.z, sd4.w};
    float4 sf4 = *(const float4*)(ssrc + (size_t)wid * 4);
    float sfv[4] = {sf4.x, sf4.y, sf4.z, sf4.w};
    float psf[4];
#pragma unroll
    for (int h = 0; h < 4; h++) {
        float e = sfv[h] + sdv[h];
        e = (e >= 0.f) ? e : 0.2f * e;
        psf[h] = __expf(e);
    }
    float pse = (hh & 2) ? ((hh & 1) ? psf[3] : psf[2]) : ((hh & 1) ? psf[1] : psf[0]);
    const unsigned short* hbase = hg + lane * 4;
    ushort4 hvs = *(const ushort4*)(hbase + (size_t)wid * 256);
    float4 acc;
    acc.x = bf2f(hvs.x) * pse; acc.y = bf2f(hvs.y) * pse;
    acc.z = bf2f(hvs.z) * pse; acc.w = bf2f(hvs.w) * pse;

    float lsum[4] = {0.f, 0.f, 0.f, 0.f};
    int beg = rs[wid], end = rs[wid + 1];
    for (int j0 = beg; j0 < end; j0 += 64) {
        int cnt = min(64, end - j0);
        if (lane < cnt) {
            int sreg = col[j0 + lane];
            float4 sv = *(const float4*)(ssrc + (size_t)sreg * 4);
            float svv[4] = {sv.x, sv.y, sv.z, sv.w};
            float pv[4];
#pragma unroll
            for (int h = 0; h < 4; h++) {
                float e = svv[h] + sdv[h];
                e = (e >= 0.f) ? e : 0.2f * e;
                pv[h] = __expf(e);
                lsum[h] += pv[h];
            }
            sl[lane] = sreg;
            *(float4*)&pl[lane * 4] = make_float4(pv[0], pv[1], pv[2], pv[3]);
        }
        int e = 0;
        for (; e + 4 <= cnt; e += 4) {
            int s0 = sl[e], s1 = sl[e + 1], s2 = sl[e + 2], s3 = sl[e + 3];
            float p0 = pl[e * 4 + hh], p1 = pl[(e + 1) * 4 + hh];
            float p2 = pl[(e + 2) * 4 + hh], p3 = pl[(e + 3) * 4 + hh];
            ushort4 h0 = *(const ushort4*)(hbase + (size_t)s0 * 256);
            ushort4 h1 = *(const ushort4*)(hbase + (size_t)s1 * 256);
            ushort4 h2 = *(const ushort4*)(hbase + (size_t)s2 * 256);
            ushort4 h3 = *(const ushort4*)(hbase + (size_t)s3 * 256);
            acc.x += bf2f(h0.x) * p0; acc.y += bf2f(h0.y) * p0;
            acc.z += bf2f(h0.z) * p0; acc.w += bf2f(h0.w) * p0;
            acc.x += bf2f(h1.x) * p1; acc.y += bf2f(h1.y) * p1;
            acc.z += bf2f(h1.z) * p1; acc.w += bf2f(h1.w) * p1;
            acc.x += bf2f(h2.x) * p2; acc.y += bf2f(h2.y) * p2;
            acc.z += bf2f(h2.z) * p2; acc.w += bf2f(h2.w) * p2;
            acc.x += bf2f(h3.x) * p3; acc.y += bf2f(h3.y) * p3;
            acc.z += bf2f(h3.z) * p3; acc.w += bf2f(h3.w) * p3;
        }
        for (; e < cnt; e++) {
            int s = sl[e];
            float p = pl[e * 4 + hh];
            ushort4 hv = *(const ushort4*)(hbase + (size_t)s * 256);
            acc.x += bf2f(hv.x) * p; acc.y += bf2f(hv.y) * p;
            acc.z += bf2f(hv.z) * p; acc.w += bf2f(hv.w) * p;
        }
    }
#pragma unroll
    for (int h = 0; h < 4; h++) {
        float v = lsum[h];
        for (int off = 32; off >= 1; off >>= 1) v += __shfl_xor(v, off, 64);
        lsum[h] = v + psf[h];
    }
    float lt = (hh & 2) ? ((hh & 1) ? lsum[3] : lsum[2]) : ((hh & 1) ? lsum[1] : lsum[0]);
    float li = 1.0f / lt;
    float4 bv = *(const float4*)(b + lane * 4);
    ushort4 o;
    o.x = f2bf(fmaxf(acc.x * li + bv.x, 0.f));
    o.y = f2bf(fmaxf(acc.y * li + bv.y, 0.f));
    o.z = f2bf(fmaxf(acc.z * li + bv.z, 0.f));
    o.w = f2bf(fmaxf(acc.w * li + bv.w, 0.f));
    *(ushort4*)(out + (size_t)wid * 256 + lane * 4) = o;
}

// ---------------------------------------------------------------------------
// Final aggregation: fused GCN2 + GAT2 over the interleaved pair buffer
// (one dword per edge per lane: lo=h2, hi=h2g). 16 lanes per node.
// ---------------------------------------------------------------------------
__global__ __launch_bounds__(256) void final_agg(const unsigned* __restrict__ hp,
                                                 const int* __restrict__ rs,
                                                 const int* __restrict__ col,
                                                 const float* __restrict__ dinv,
                                                 const float* __restrict__ s2s,
                                                 const float* __restrict__ s2d,
                                                 const float* __restrict__ bg2,
                                                 const float* __restrict__ bga2,
                                                 float* __restrict__ out) {
    int t = blockIdx.x * 256 + threadIdx.x;
    int node = t >> 4;
    int c = t & 15;
    float di = dinv[node];
    float sd = s2d[node];
    float es = s2s[node] + sd;
    es = (es >= 0.f) ? es : 0.2f * es;
    float psf = __expf(es);
    unsigned pvs = hp[(size_t)node * 16 + c];
    float accg = bf2f((unsigned short)pvs);
    float acca = bf2f((unsigned short)(pvs >> 16)) * psf;
    float lp = 0.f;
    int beg = rs[node], end = rs[node + 1];
    for (int j0 = beg; j0 < end; j0 += 16) {
        int cnt = min(16, end - j0);
        int sreg = 0;
        float pr = 0.f;
        if (c < cnt) {
            sreg = col[j0 + c];
            float e = s2s[sreg] + sd;
            e = (e >= 0.f) ? e : 0.2f * e;
            pr = __expf(e);
            lp += pr;
        }
        for (int e = 0; e < cnt; e += 4) {
            int si[4];
            float pi[4];
#pragma unroll
            for (int u = 0; u < 4; u++) {
                si[u] = __shfl(sreg, (e + u) & 15, 16);  // sources active in-group
                pi[u] = __shfl(pr, (e + u) & 15, 16);
            }
            unsigned hv[4];
#pragma unroll
            for (int u = 0; u < 4; u++) hv[u] = hp[(size_t)si[u] * 16 + c];
#pragma unroll
            for (int u = 0; u < 4; u++) {
                if (e + u < cnt) {
                    accg += bf2f((unsigned short)hv[u]);
                    acca += bf2f((unsigned short)(hv[u] >> 16)) * pi[u];
                }
            }
        }
    }
    for (int off = 8; off >= 1; off >>= 1) lp += __shfl_xor(lp, off, 16);
    float l = lp + psf;
    out[(size_t)node * 32 + c] = accg * di + bg2[c];
    out[(size_t)node * 32 + 16 + c] = acca / l + bga2[c];
}

// ---------------------------------------------------------------------------
// Launch
// ---------------------------------------------------------------------------
extern "C" void kernel_launch(void* const* d_in, const int* in_sizes, int n_in,
                              void* d_out, int out_size, void* d_ws, size_t ws_size,
                              hipStream_t stream) {
    const float* x      = (const float*)d_in[0];
    const int*   ei     = (const int*)d_in[1];
    const float* Wg1    = (const float*)d_in[2];
    const float* bg1    = (const float*)d_in[3];
    const float* Wg2    = (const float*)d_in[4];
    const float* bg2    = (const float*)d_in[5];
    const float* Wgat1  = (const float*)d_in[6];
    const float* a_src1 = (const float*)d_in[7];
    const float* a_dst1 = (const float*)d_in[8];
    const float* bgat1  = (const float*)d_in[9];
    const float* Wgat2  = (const float*)d_in[10];
    const float* a_src2 = (const float*)d_in[11];
    const float* a_dst2 = (const float*)d_in[12];
    const float* bgat2  = (const float*)d_in[13];
    float* out = (float*)d_out;

    const int* e_src = ei;
    const int* e_dst = ei + EE;

    char* wsb = (char*)d_ws;
    size_t o = 0;
    auto alloc = [&](size_t bytes) -> void* {
        void* p = wsb + o;
        o += (bytes + 255) & ~(size_t)255;
        return p;
    };
    float* dinv            = (float*)alloc(NN * 4);
    float* ssrc1           = (float*)alloc((size_t)NN * 16);
    float* sdst1           = (float*)alloc((size_t)NN * 16);
    unsigned short* h1b    = (unsigned short*)alloc((size_t)NN * HH * 2);
    unsigned short* xg1    = (unsigned short*)alloc((size_t)NN * HH * 2);
    unsigned short* hgb    = (unsigned short*)alloc((size_t)NN * 256 * 2);
    unsigned short* xgat1  = (unsigned short*)alloc((size_t)NN * 256 * 2);
    unsigned short* pairb  = (unsigned short*)alloc((size_t)NN * 16 * 4);  // interleaved h2|h2g
    float* s2src           = (float*)alloc(NN * 4);
    float* s2dst           = (float*)alloc(NN * 4);
    unsigned short* bhiC   = (unsigned short*)alloc((size_t)8 * NTT * 512 * 2);  // combined Wg1+Wgat1
    unsigned short* bloC   = (unsigned short*)alloc((size_t)8 * NTT * 512 * 2);
    unsigned short* bhiG2  = (unsigned short*)alloc(64 * 16 * 2);
    unsigned short* bloG2  = (unsigned short*)alloc(64 * 16 * 2);
    unsigned short* bhiA2  = (unsigned short*)alloc(256 * 16 * 2);
    unsigned short* bloA2  = (unsigned short*)alloc(256 * 16 * 2);
    int* cnt               = (int*)alloc(NN * 4);
    int* rowstart          = (int*)alloc((NN + 1) * 4);
    int* cursor            = (int*)alloc(NN * 4);
    int* colarr            = (int*)alloc((size_t)EE * 4);
    int* partial           = (int*)alloc(256 * 4);
    int* blockoff          = (int*)alloc(256 * 4);

    const int TB = 256;
    const int NB = (NN + 255) / 256;
    // CSR build + weight packing
    k_zero_int<<<(NN + TB - 1) / TB, TB, 0, stream>>>(cnt, NN);
    k_count<<<(EE + TB - 1) / TB, TB, 0, stream>>>(e_dst, cnt, EE);
    k_scan_a<<<NB, TB, 0, stream>>>(cnt, partial, NN);
    k_scan_b<<<1, TB, 0, stream>>>(partial, blockoff, rowstart + NN, NB);
    k_scan_c<<<NB, TB, 0, stream>>>(cnt, blockoff, rowstart, cursor, dinv, NN);
    k_fill<<<(EE + TB - 1) / TB, TB, 0, stream>>>(e_src, e_dst, cursor, colarr, EE);
    k_pack_w<8, 4, NTT, 0><<<(8 * 4 * 64 + TB - 1) / TB, TB, 0, stream>>>(Wg1, bhiC, bloC);
    k_pack_w<8, 16, NTT, 4><<<(8 * 16 * 64 + TB - 1) / TB, TB, 0, stream>>>(Wgat1, bhiC, bloC);
    k_pack_w<2, 1, 1, 0><<<1, TB, 0, stream>>>(Wg2, bhiG2, bloG2);
    k_pack_w<8, 1, 1, 0><<<2, TB, 0, stream>>>(Wgat2, bhiA2, bloA2);

    const int GB = (NN + 63) / 64;    // 782
    const int G16 = (NN * 16) / 256;  // exact: 3125

    // Fused big GEMM: h1b (scaled) + hgb + s1 scores in ONE pass over x
    mfma_gemm_fused<<<GB, TB, 0, stream>>>(x, bhiC, bloC, h1b, hgb, dinv,
                                           a_src1, a_dst1, ssrc1, sdst1, NN);

    // GCN path
    gcn1_agg<<<(NN * 64) / TB, TB, 0, stream>>>(h1b, rowstart, colarr, dinv, bg1, xg1);
    mfma_n16<2, true, false, 0><<<GB, TB, 0, stream>>>(xg1, bhiG2, bloG2, pairb, dinv,
                                                       nullptr, nullptr, nullptr, nullptr, NN);

    // GAT path
    gat1_agg<<<NN / 4, TB, 0, stream>>>(hgb, rowstart, colarr, ssrc1, sdst1, bgat1, xgat1);
    mfma_n16<8, false, true, 1><<<GB, TB, 0, stream>>>(xgat1, bhiA2, bloA2, pairb, nullptr,
                                                       a_src2, a_dst2, s2src, s2dst, NN);

    // Fused GCN2+GAT2 aggregation -> d_out
    final_agg<<<G16, TB, 0, stream>>>((const unsigned*)pairb, rowstart, colarr, dinv,
                                      s2src, s2dst, bg2, bgat2, out);
}